// Round 9
// baseline (159.324 us; speedup 1.0000x reference)
//
#include <hip/hip_runtime.h>
#include <math.h>

// FFTConvReservoir: y = tanh(ifft(fft(u)*fft(K)).real + D*u); B=8,H=256,L=8192 fp32.
// Round 17: three surgical changes to the verified R16 conv (structure untouched):
// 1) launch_bounds (512,4)->(512,2): LDS caps residency at 2 blocks/CU anyway;
//    the old bound pinned VGPR=64 (measured exactly at cap) and over-constrained
//    regalloc. True budget is 128.
// 2) Pyramid sharing: M1'/M2' pyramids are conjugates of M1/M2's, M3's twu =
//    conj(twd). Apply inverses via dit_apply_c (wi negation = free VOP3 input
//    modifier): 6 pyramid fills -> 2 fills + 1 const. ~8% VALU cut. Twiddle-fill
//    was ~30% of butterfly work (sincos + cmul chains).
// 3) Grid 1024->512, two batch-pairs per block (same h): kw loaded once, reused
//    from registers (-8MB HBM); halved prologues; grid = exactly one residency
//    wave (512 = 2/CU * 256 CU).
// kfft: R15/R16 fused kernel verbatim (verified).
// Evidence basis: R15+R16 proved conv is latency/instruction-bound, not
// bank-conflict-bound (swizzle choice = no effect; SQ_LDS_BANK_CONFLICT counter
// unreliable here - exact powers of 2). Non-conv residual ~97us invariant ->
// fixed overhead; conv is the only lever.
// Lessons kept: no b64 LDS (R7), kw=(FFT(K)+D)/N folded (R6), scalar b32 LDS
// (R3), launch_bounds 2nd arg = min blocks/CU (R11/R12), no cooperative launch
// (R14), NT=512 5-pass wave-private middle (R9/R15), no radix-16 middle (R15).

#define LL 8192
#define NT 512
#define HH 256
#define TWO_PI 6.2831853071795864f
#define CP8  0.92387953251129f    // cos(pi/8)
#define SP8  0.38268343236509f    // sin(pi/8)
#define CP4  0.70710678118654752f // cos(pi/4)
#define SP4  0.70710678118654752f // sin(pi/4)

// conv swizzle SW6 (R16, verified-neutral): bits[4:3]^=e[8:7], bits[2:0]^=e[7:5].
__device__ __forceinline__ int SW(int e) {
    return e ^ ((e >> 4) & 0x18) ^ ((e >> 5) & 0x07);
}
// kfft swizzle (2048-elem LDS): bits[4:2] ^= e[7:5]. Verified R13.
__device__ __forceinline__ int SW2(int e) {
    return e ^ (((e >> 5) & 7) << 2);
}
__device__ __forceinline__ float fast_tanh(float x) {
    float e = __expf(2.0f * x);
    return 1.0f - 2.0f / (e + 1.0f);
}

// Twiddle pyramid: level j at offset (1<<j)-1, length 2^j; top level chained cmul,
// lower levels by squaring. conj distributes over mul/square, so the conjugate
// pyramid = entrywise conj -> inverse passes reuse the forward pyramid via
// dit_apply_c.
template<int JT>
__device__ __forceinline__ void fill_pyr_cs(float c0, float s0, float Er, float Ei,
                                            float* twr, float* twi) {
    const int off = (1 << JT) - 1;
    twr[off] = c0; twi[off] = s0;
    #pragma unroll
    for (int m = 1; m < (1 << JT); ++m) {
        const float pr = twr[off + m - 1], pi = twi[off + m - 1];
        twr[off + m] = pr * Er - pi * Ei;
        twi[off + m] = pr * Ei + pi * Er;
    }
    #pragma unroll
    for (int j = JT - 1; j >= 0; --j) {
        #pragma unroll
        for (int m = 0; m < (1 << j); ++m) {
            const float a = twr[(2 << j) - 1 + m], b = twi[(2 << j) - 1 + m];
            twr[(1 << j) - 1 + m] = a * a - b * b;
            twi[(1 << j) - 1 + m] = 2.0f * a * b;
        }
    }
}
template<int JT>
__device__ __forceinline__ void fill_pyr(float ang0, float Er, float Ei,
                                         float* twr, float* twi) {
    float s, c;
    __sincosf(ang0, &s, &c);
    fill_pyr_cs<JT>(c, s, Er, Ei, twr, twi);
}

template<int R2>
__device__ __forceinline__ void dif_apply(float* xr, float* xi,
                                          const float* twr, const float* twi) {
    #pragma unroll
    for (int j = R2 - 1; j >= 0; --j) {
        #pragma unroll
        for (int q = 0; q < (1 << (R2 - 1)); ++q) {
            const int mm = q & ((1 << j) - 1);
            const int m0 = ((q >> j) << (j + 1)) | mm;
            const int m1 = m0 + (1 << j);
            const float wr = twr[(1 << j) - 1 + mm], wi = twi[(1 << j) - 1 + mm];
            const float ar = xr[m0], ai = xi[m0], br = xr[m1], bi = xi[m1];
            xr[m0] = ar + br; xi[m0] = ai + bi;
            const float dr = ar - br, di = ai - bi;
            xr[m1] = dr * wr - di * wi;
            xi[m1] = dr * wi + di * wr;
        }
    }
}
template<int R2>
__device__ __forceinline__ void dit_apply(float* xr, float* xi,
                                          const float* twr, const float* twi) {
    #pragma unroll
    for (int j = 0; j < R2; ++j) {
        #pragma unroll
        for (int q = 0; q < (1 << (R2 - 1)); ++q) {
            const int mm = q & ((1 << j) - 1);
            const int m0 = ((q >> j) << (j + 1)) | mm;
            const int m1 = m0 + (1 << j);
            const float wr = twr[(1 << j) - 1 + mm], wi = twi[(1 << j) - 1 + mm];
            const float br = xr[m1] * wr - xi[m1] * wi;
            const float bi = xr[m1] * wi + xi[m1] * wr;
            const float ar = xr[m0], ai = xi[m0];
            xr[m0] = ar + br; xi[m0] = ai + bi;
            xr[m1] = ar - br; xi[m1] = ai - bi;
        }
    }
}
// dit with conjugated twiddles (reuse forward pyramid; negation is free VOP3 mod).
template<int R2>
__device__ __forceinline__ void dit_apply_c(float* xr, float* xi,
                                            const float* twr, const float* twi) {
    #pragma unroll
    for (int j = 0; j < R2; ++j) {
        #pragma unroll
        for (int q = 0; q < (1 << (R2 - 1)); ++q) {
            const int mm = q & ((1 << j) - 1);
            const int m0 = ((q >> j) << (j + 1)) | mm;
            const int m1 = m0 + (1 << j);
            const float wr = twr[(1 << j) - 1 + mm], wi = -twi[(1 << j) - 1 + mm];
            const float br = xr[m1] * wr - xi[m1] * wi;
            const float bi = xr[m1] * wi + xi[m1] * wr;
            const float ar = xr[m0], ai = xi[m0];
            xr[m0] = ar + br; xi[m0] = ai + bi;
            xr[m1] = ar - br; xi[m1] = ai - bi;
        }
    }
}

// ---------------- conv building blocks (R9/R13 structure, NT=512) ----------

__device__ __forceinline__ void fwd_A(float* xr, float* xi, int tid,
                                      float* re, float* im) {
    float twr[15], twi[15];
    fill_pyr<3>(-(TWO_PI / 8192.0f) * (float)tid, CP8, -SP8, twr, twi);
    dif_apply<4>(xr, xi, twr, twi);
    #pragma unroll
    for (int m = 0; m < 16; ++m) {
        const int p = SW(tid + (m << 9));
        re[p] = xr[m]; im[p] = xi[m];
    }
}

// M1: spans 256/128/64. Pyramid passed in (fwd sign); INV applies conjugate.
template<bool INV>
__device__ __forceinline__ void mid_M1p(float* re, float* im, int lane, int wv,
                                        const float* twr, const float* twi) {
    #pragma unroll
    for (int r = 0; r < 2; ++r) {
        const int base = (((wv << 1) | r) << 9) + lane;
        float ar[8], ai[8];
        #pragma unroll
        for (int j = 0; j < 8; ++j) {
            const int p = SW(base + (j << 6));
            ar[j] = re[p]; ai[j] = im[p];
        }
        if (INV) dit_apply_c<3>(ar, ai, twr, twi);
        else     dif_apply<3>(ar, ai, twr, twi);
        #pragma unroll
        for (int j = 0; j < 8; ++j) {
            const int p = SW(base + (j << 6));
            re[p] = ar[j]; im[p] = ai[j];
        }
    }
}

// M2: spans 32/16/8. Pyramid passed in (fwd sign); INV applies conjugate.
template<bool INV>
__device__ __forceinline__ void mid_M2p(float* re, float* im, int lane, int wv,
                                        const float* twr, const float* twi) {
    const int sub = ((lane >> 3) << 6) + (lane & 7);
    #pragma unroll
    for (int r = 0; r < 2; ++r) {
        const int base = (((wv << 1) | r) << 9) + sub;
        float ar[8], ai[8];
        #pragma unroll
        for (int j = 0; j < 8; ++j) {
            const int p = SW(base + (j << 3));
            ar[j] = re[p]; ai[j] = im[p];
        }
        if (INV) dit_apply_c<3>(ar, ai, twr, twi);
        else     dif_apply<3>(ar, ai, twr, twi);
        #pragma unroll
        for (int j = 0; j < 8; ++j) {
            const int p = SW(base + (j << 3));
            re[p] = ar[j]; im[p] = ai[j];
        }
    }
}

// launch_bounds (512,2): LDS caps at 2 blocks/CU; VGPR budget 128 (was 64).
__global__ __launch_bounds__(NT, 2) void conv_kernel(const float* __restrict__ u,
                                                     const float2* __restrict__ Kf,
                                                     float* __restrict__ out) {
    __shared__ float re[LL];
    __shared__ float im[LL];
    const int tid = threadIdx.x;
    const int h = blockIdx.x & (HH - 1);
    const int pr0 = blockIdx.x >> 8;        // 0 or 1; instances do pr0, pr0+2
    const int lane = tid & 63, wv = tid >> 6;
    const int c0 = (wv << 1);               // wave's chunks: c0, c0+1
    const float2* kf = Kf + (size_t)h * LL;

    float kwr[2][8], kwi[2][8];             // loaded in inst 0, reused in inst 1

    #pragma unroll
    for (int inst = 0; inst < 2; ++inst) {
        const int pr_ = pr0 + (inst << 1);
        const size_t off0 = ((size_t)(pr_ * 2) * HH + h) * LL;
        const size_t off1 = off0 + (size_t)HH * LL;
        const float* u0 = u + off0;
        const float* u1 = u + off1;

        float xr[16], xi[16];
        #pragma unroll
        for (int m = 0; m < 16; ++m) {
            xr[m] = u0[tid + (m << 9)];
            xi[m] = u1[tid + (m << 9)];
        }
        if (inst) __syncthreads();        // prior instance's A'-reads done
        fwd_A(xr, xi, tid, re, im);       // z = u0 + i*u1
        __syncthreads();

        if (inst == 0) {
            #pragma unroll
            for (int r = 0; r < 2; ++r) {
                const int eb = ((c0 | r) << 9) + (lane << 3);
                const float4* kp = (const float4*)(kf + eb);
                #pragma unroll
                for (int jj = 0; jj < 4; ++jj) {
                    const float4 v = kp[jj];
                    kwr[r][2 * jj] = v.x;     kwi[r][2 * jj] = v.y;
                    kwr[r][2 * jj + 1] = v.z; kwi[r][2 * jj + 1] = v.w;
                }
            }
        }

        // ---- wave-private middle: no __syncthreads until pass A' ----
        // Pyramids filled once (fwd sign); inverse passes use dit_apply_c.
        float p1r[7], p1i[7];
        fill_pyr<2>(-(TWO_PI / 512.0f) * (float)lane, CP4, -SP4, p1r, p1i);
        mid_M1p<false>(re, im, lane, wv, p1r, p1i);

        float p2r[7], p2i[7];
        fill_pyr<2>(-(TWO_PI / 64.0f) * (float)(lane & 7), CP4, -SP4, p2r, p2i);
        mid_M2p<false>(re, im, lane, wv, p2r, p2i);

        // Merged M3: spans 4/2/1 fwd, *kw, inverse 1/2/4 (conjugate of same
        // constant pyramid).
        {
            float twd_r[7], twd_i[7];
            fill_pyr_cs<2>(1.0f, 0.0f, CP4, -SP4, twd_r, twd_i);
            #pragma unroll
            for (int r = 0; r < 2; ++r) {
                const int eb = ((c0 | r) << 9) + (lane << 3);
                float yr[8], yi[8];
                #pragma unroll
                for (int j = 0; j < 8; ++j) {
                    const int p = SW(eb + j);
                    yr[j] = re[p]; yi[j] = im[p];
                }
                dif_apply<3>(yr, yi, twd_r, twd_i);
                #pragma unroll
                for (int j = 0; j < 8; ++j) {
                    const float a = yr[j], b = yi[j];
                    yr[j] = a * kwr[r][j] - b * kwi[r][j];
                    yi[j] = a * kwi[r][j] + b * kwr[r][j];
                }
                dit_apply_c<3>(yr, yi, twd_r, twd_i);
                #pragma unroll
                for (int j = 0; j < 8; ++j) {
                    const int p = SW(eb + j);
                    re[p] = yr[j]; im[p] = yi[j];
                }
            }
        }

        mid_M2p<true>(re, im, lane, wv, p2r, p2i);
        mid_M1p<true>(re, im, lane, wv, p1r, p1i);
        __syncthreads();

        // Inv pass A' (spans 512..4096) + epilogue (skip/norm folded into kw).
        {
            float twr[15], twi[15];
            #pragma unroll
            for (int m = 0; m < 16; ++m) {
                const int p = SW(tid + (m << 9));
                xr[m] = re[p]; xi[m] = im[p];
            }
            fill_pyr<3>((TWO_PI / 8192.0f) * (float)tid, CP8, SP8, twr, twi);
            dit_apply<4>(xr, xi, twr, twi);
        }
        float* o0 = out + off0;
        float* o1 = out + off1;
        #pragma unroll
        for (int m = 0; m < 16; ++m) {
            const int n = tid + (m << 9);
            o0[n] = fast_tanh(xr[m]);
            o1[n] = fast_tanh(xi[m]);
        }
    }
}

// ---------------- kfft: one kernel, quadrant combine + 2048-pt chunk FFT --------
// Block (h = b>>2, cq = b&3), NT=256, 16 KB LDS, 1 barrier. Verified R15/R16.
__global__ __launch_bounds__(256) void kfftF_kernel(const float* __restrict__ K,
                                                    const float* __restrict__ D,
                                                    float2* __restrict__ Kf) {
    __shared__ float re[2048];
    __shared__ float im[2048];
    const int b = blockIdx.x;
    const int h = b >> 2, cq = b & 3;
    const int tid = threadIdx.x;
    const float* Kr = K + (size_t)h * LL;

    float xr[8], xi[8];
    #pragma unroll
    for (int j = 0; j < 8; ++j) {
        const int m = tid + (j << 8);                  // [0,2048)
        const float A  = Kr[m];
        const float Bv = Kr[m + 2048];
        const float C  = Kr[m + 4096];
        const float E  = Kr[m + 6144];
        if (cq == 0) {
            xr[j] = A + C + Bv + E; xi[j] = 0.0f;
        } else {
            float sn, cs;
            __sincosf(-(TWO_PI / 8192.0f) * (float)m, &sn, &cs);
            if (cq == 1) {
                const float dif = A + C - Bv - E;
                const float c2 = cs * cs - sn * sn, s2 = 2.0f * cs * sn;
                xr[j] = dif * c2; xi[j] = dif * s2;
            } else {
                const float p_ = A - C, q_ = Bv - E;
                if (cq == 2) {
                    xr[j] = p_ * cs + q_ * sn; xi[j] = p_ * sn - q_ * cs;
                } else {
                    const float c2 = cs * cs - sn * sn, s2 = 2.0f * cs * sn;
                    const float c3 = cs * c2 - sn * s2, s3 = cs * s2 + sn * c2;
                    xr[j] = p_ * c3 - q_ * s3; xi[j] = p_ * s3 + q_ * c3;
                }
            }
        }
    }
    {
        float twr[7], twi[7];
        fill_pyr<2>(-(TWO_PI / 2048.0f) * (float)tid, CP4, -SP4, twr, twi);
        dif_apply<3>(xr, xi, twr, twi);
    }
    #pragma unroll
    for (int j = 0; j < 8; ++j) {
        const int p = SW2(tid + (j << 8));
        re[p] = xr[j]; im[p] = xi[j];
    }
    __syncthreads();
    {
        const int t_ = tid & 31, sub = tid >> 5;
        float twr[7], twi[7];
        fill_pyr<2>(-(TWO_PI / 256.0f) * (float)t_, CP4, -SP4, twr, twi);
        const int be = (sub << 8) + t_;
        float ar[8], ai[8];
        #pragma unroll
        for (int j = 0; j < 8; ++j) {
            const int p = SW2(be + (j << 5));
            ar[j] = re[p]; ai[j] = im[p];
        }
        dif_apply<3>(ar, ai, twr, twi);
        #pragma unroll
        for (int j = 0; j < 8; ++j) {
            const int p = SW2(be + (j << 5));
            re[p] = ar[j]; im[p] = ai[j];
        }
    }
    // M1 -> M2 handoff same-wave (verified R13): no barrier.
    {
        const int blk = tid >> 2, r = tid & 3;
        float twr[7], twi[7];
        fill_pyr<2>(-(TWO_PI / 32.0f) * (float)r, CP4, -SP4, twr, twi);
        const int eb = (blk << 5) + r;
        float yr[8], yi[8];
        #pragma unroll
        for (int j = 0; j < 8; ++j) {
            const int p = SW2(eb + (j << 2));
            yr[j] = re[p]; yi[j] = im[p];
        }
        dif_apply<3>(yr, yi, twr, twi);
        const float s2_ = (r < 2) ? 1.0f : -1.0f;
        #pragma unroll
        for (int j = 0; j < 8; ++j) {
            const float vr = __shfl_xor(yr[j], 2);
            const float vi = __shfl_xor(yi[j], 2);
            const float tr = fmaf(yr[j], s2_, vr);
            const float ti = fmaf(yi[j], s2_, vi);
            yr[j] = (r == 3) ? ti : tr;
            yi[j] = (r == 3) ? -tr : ti;
        }
        const float s1_ = (r & 1) ? -1.0f : 1.0f;
        #pragma unroll
        for (int j = 0; j < 8; ++j) {
            const float vr = __shfl_xor(yr[j], 1);
            const float vi = __shfl_xor(yi[j], 1);
            yr[j] = fmaf(yr[j], s1_, vr);
            yi[j] = fmaf(yi[j], s1_, vi);
        }
        const float dh = D[h];
        const float invN = 1.0f / (float)LL;
        float2* baseo = Kf + (size_t)h * LL + (cq << 11);
        #pragma unroll
        for (int j = 0; j < 8; ++j) {
            baseo[eb + (j << 2)] = make_float2((yr[j] + dh) * invN, yi[j] * invN);
        }
    }
}

extern "C" void kernel_launch(void* const* d_in, const int* in_sizes, int n_in,
                              void* d_out, int out_size, void* d_ws, size_t ws_size,
                              hipStream_t stream) {
    const float* u = (const float*)d_in[0];   // (8, 256, 8192)
    const float* K = (const float*)d_in[1];   // (256, 8192)
    const float* D = (const float*)d_in[2];   // (256,)
    float* out = (float*)d_out;               // (8, 256, 8192)
    float2* Kf = (float2*)d_ws;               // 256 * 8192 float2 = 16 MB

    kfftF_kernel<<<dim3(4 * HH), dim3(256), 0, stream>>>(K, D, Kf);
    conv_kernel<<<dim3(2 * HH), dim3(NT), 0, stream>>>(u, Kf, out);
}